// Round 4
// baseline (236.297 us; speedup 1.0000x reference)
//
#include <hip/hip_runtime.h>

// Morton decode: out[b,c,i,j] = x[b,c,ij], i = odd bits of ij, j = even bits.
// B=8, C=64, L=65536 (S=256), fp32.
//
// R3 post-mortem: register-shuffle kernel stores 8x128B scattered segments per
// wave instruction -> ~2.5 TB/s (HBM row-buffer thrash). fillBuffer hits
// 6.7 TB/s at 9% occupancy with linear writes -> linearity, not occupancy, is
// what matters.
//
// This version: block = one 32-row x 256-col output stripe (32 KB).
//  - Source of a stripe = 4 contiguous 8 KB Morton chunks (source bits 0..10
//    are exactly {j0,i0,...,i4,j5}; j6->bit12, j7->bit14) -> linear b128 reads.
//  - Stage through 32 KB LDS with XOR quad-swizzle (bank-uniform both phases).
//  - Write: wave w writes rows 8w..8w+7; each store instruction is one FULL
//    1 KB-contiguous row (64 lanes x float4). Block writes a contiguous 32 KB
//    region; 4 consecutive stripes per block -> 128 KB linear read + write
//    regions per block. 1024 blocks x 256 threads.

typedef float f32x4 __attribute__((ext_vector_type(4)));

__device__ __forceinline__ unsigned swz(unsigned q) {
    // XOR low quad-bank bits with lane-varying high bits: bit0 ^= bit4, bit1 ^= bit6
    return q ^ ((q >> 4) & 1u) ^ (((q >> 6) & 1u) << 1);
}

__global__ __launch_bounds__(256) void Morton_decode_69312182223578_kernel(
        const float* __restrict__ x, float* __restrict__ out) {
    __shared__ f32x4 lds[2048];   // 32 KB, quad-granular, swizzled

    const unsigned t = threadIdx.x;
    const unsigned w = t >> 6;    // wave 0..3
    const unsigned l = t & 63u;   // lane 0..63

    // 4096 stripe-tasks = 512 images x 8 stripes (32 rows each).
    // Block handles 4 consecutive stripes.
    const unsigned task0 = blockIdx.x * 4u;
    for (unsigned task = task0; task < task0 + 4u; ++task) {
        const unsigned img = task >> 3;   // 0..511
        const unsigned s   = task & 7u;   // stripe index = (i5,i6,i7)
        const size_t img_base = (size_t)img << 16;
        const size_t src_base = img_base + ((size_t)(s & 1u) << 11)
                                         + ((size_t)((s >> 1) & 1u) << 13)
                                         + ((size_t)(s >> 2) << 15);
        const size_t dst_base = img_base + ((size_t)s << 13);  // 32 rows * 256

        // ---- read phase: 2048 quads, contiguous within 512-quad chunks ----
        #pragma unroll
        for (unsigned k = 0; k < 8; ++k) {
            const unsigned qw = k * 256u + t;   // packed quad index in stripe
            // unpack: bits 0..8 stay; bit9 = j6 -> global quad bit10;
            //         bit10 = j7 -> global quad bit12
            const unsigned gq = (qw & 511u) | ((qw & 512u) << 1) | ((qw & 1024u) << 2);
            const f32x4 v = *(const f32x4*)(x + src_base + ((size_t)gq << 2));
            lds[swz(qw)] = v;
        }
        __syncthreads();

        // ---- write phase: wave w writes rows 8w..8w+7; 1 KB-linear stores ----
        #pragma unroll
        for (unsigned k = 0; k < 4; ++k) {
            const unsigned m = w * 4u + k;      // row pair -> rows 2m, 2m+1
            // packed quad-pair index K bits: 0:m0 1:l0 2:m1 3:l1 4:m2 5:l2
            //                                6:m3 7:l3 8:l4 9:l5
            const unsigned K = (m & 1u) | ((l & 1u) << 1)
                             | (((m >> 1) & 1u) << 2) | (((l >> 1) & 1u) << 3)
                             | (((m >> 2) & 1u) << 4) | (((l >> 2) & 1u) << 5)
                             | ((m >> 3) << 6) | ((l >> 3) << 7);
            const f32x4 qA = lds[swz(2u * K)];        // rows 2m,2m+1 cols 4l,4l+1
            const f32x4 qB = lds[swz(2u * K + 1u)];   // rows 2m,2m+1 cols 4l+2,4l+3
            const f32x4 top = {qA.x, qA.y, qB.x, qB.y};
            const f32x4 bot = {qA.z, qA.w, qB.z, qB.w};
            float* p = out + dst_base + ((size_t)(2u * m) << 8) + 4u * l;
            *(f32x4*)p         = top;
            *(f32x4*)(p + 256) = bot;
        }
        __syncthreads();
    }
}

extern "C" void kernel_launch(void* const* d_in, const int* in_sizes, int n_in,
                              void* d_out, int out_size, void* d_ws, size_t ws_size,
                              hipStream_t stream) {
    const float* x = (const float*)d_in[0];
    float* out = (float*)d_out;
    // 1024 blocks x 4 stripe-tasks = 4096 stripes = 512 images x 8 stripes
    Morton_decode_69312182223578_kernel<<<1024, 256, 0, stream>>>(x, out);
}